// Round 11
// baseline (65.425 us; speedup 1.0000x reference)
//
#include <hip/hip_runtime.h>

#define NSITES 784
#define BS_TOT 16384
#define KSEG 16
#define GSEG 49     // 16*49 = 784; 49 = 12 quads * 4 + 1 site
#define NQUAD 12

typedef unsigned long long u64;

// ---------------- per-site step, parameterized vars (round-0 verified math) ----------------
// t_ -> site tensor (32 floats, layout [l][r][p], flat l*8+r*2+p). Block-uniform -> s_load.
#define STEPV(sbit, TP, L0,L1,L2,L3, AN, AL) do {                                    \
    const float* t_ = (TP);                                                          \
    float p00 = fmaf(L0, t_[0],  fmaf(L1, t_[8],  fmaf(L2, t_[16], L3 * t_[24])));   \
    float p01 = fmaf(L0, t_[1],  fmaf(L1, t_[9],  fmaf(L2, t_[17], L3 * t_[25])));   \
    float p10 = fmaf(L0, t_[2],  fmaf(L1, t_[10], fmaf(L2, t_[18], L3 * t_[26])));   \
    float p11 = fmaf(L0, t_[3],  fmaf(L1, t_[11], fmaf(L2, t_[19], L3 * t_[27])));   \
    float p20 = fmaf(L0, t_[4],  fmaf(L1, t_[12], fmaf(L2, t_[20], L3 * t_[28])));   \
    float p21 = fmaf(L0, t_[5],  fmaf(L1, t_[13], fmaf(L2, t_[21], L3 * t_[29])));   \
    float p30 = fmaf(L0, t_[6],  fmaf(L1, t_[14], fmaf(L2, t_[22], L3 * t_[30])));   \
    float p31 = fmaf(L0, t_[7],  fmaf(L1, t_[15], fmaf(L2, t_[23], L3 * t_[31])));   \
    bool s_ = (sbit);                                                                \
    float mx_ = fmaxf(p00, p01);                                                     \
    float ch_ = s_ ? p00 : p01;                                                      \
    AN += (ch_ - mx_);                                                               \
    float ad_ = fabsf(p00 - p01);                                                    \
    AL += __builtin_amdgcn_logf(1.0f + __builtin_amdgcn_exp2f(-ad_ * 1.4426950408889634f)); \
    L0 = s_ ? p00 : p01;                                                             \
    L1 = s_ ? p10 : p11;                                                             \
    L2 = s_ ? p20 : p21;                                                             \
    L3 = s_ ? p30 : p31;                                                             \
} while (0)

#define STEP(sbit, TP) STEPV(sbit, TP, left0,left1,left2,left3, acc_nat, acc_l2)

// Q_row = P_row * M  (rows of M in float4 m0..m3)
#define MM_ROW(Q, Pr) do {                                                           \
    Q.x = fmaf(Pr.x, m0.x, fmaf(Pr.y, m1.x, fmaf(Pr.z, m2.x, Pr.w * m3.x)));         \
    Q.y = fmaf(Pr.x, m0.y, fmaf(Pr.y, m1.y, fmaf(Pr.z, m2.y, Pr.w * m3.y)));         \
    Q.z = fmaf(Pr.x, m0.z, fmaf(Pr.y, m1.z, fmaf(Pr.z, m2.z, Pr.w * m3.z)));         \
    Q.w = fmaf(Pr.x, m0.w, fmaf(Pr.y, m1.w, fmaf(Pr.z, m2.w, Pr.w * m3.w)));         \
} while (0)

#define MM4(P0,P1,P2,P3) do { float4 Q0,Q1,Q2,Q3; \
    MM_ROW(Q0,P0); MM_ROW(Q1,P1); MM_ROW(Q2,P2); MM_ROW(Q3,P3); \
    P0=Q0; P1=Q1; P2=Q2; P3=Q3; } while (0)

// ================= kernel 1: fused [pp_qq (16 blocks)] + [pack (4096 blocks)] =========
// pp_qq: QQ[k*12+q][c][a*4+b] = prod of 4 selected site matrices (c = 4 data bits, bit->phys0)
// pack:  packed[w][b] bit j = (data[b][w*64+j] == 1.0f)
__global__ __launch_bounds__(256) void fused_pre_kernel(const float* __restrict__ tensors,
                                                        const float* __restrict__ data,
                                                        float* __restrict__ QQ,
                                                        u64* __restrict__ packed) {
    if (blockIdx.x < KSEG) {
        // ---- pp_qq for segment k (data-independent) ----
        __shared__ float sPP[24][4][16];
        const int k = blockIdx.x;
        const int t = threadIdx.x;
        const int n0 = k * GSEG;

        if (t < 96) {                      // 24 pairs x 4 combos
            const int j = t >> 2, c2 = t & 3;
            const float* t0 = tensors + (size_t)(n0 + 2 * j) * 32;
            const float* t1 = tensors + (size_t)(n0 + 2 * j + 1) * 32;
            const int p0 = (c2 & 1) ? 0 : 1;
            const int p1 = (c2 & 2) ? 0 : 1;
            float A[4][4], B[4][4];
            #pragma unroll
            for (int l = 0; l < 4; ++l)
                #pragma unroll
                for (int r = 0; r < 4; ++r) {
                    A[l][r] = t0[l * 8 + r * 2 + p0];
                    B[l][r] = t1[l * 8 + r * 2 + p1];
                }
            #pragma unroll
            for (int a = 0; a < 4; ++a)
                #pragma unroll
                for (int bb = 0; bb < 4; ++bb)
                    sPP[j][c2][a * 4 + bb] =
                        fmaf(A[a][0], B[0][bb], fmaf(A[a][1], B[1][bb],
                        fmaf(A[a][2], B[2][bb], A[a][3] * B[3][bb])));
        }
        __syncthreads();

        if (t < 192) {                     // 12 quads x 16 combos
            const int q = t >> 4, c = t & 15;
            const float* A = sPP[2 * q][c & 3];
            const float* B = sPP[2 * q + 1][(c >> 2) & 3];
            float* dst = QQ + ((size_t)(k * NQUAD + q) * 16 + c) * 16;
            #pragma unroll
            for (int a = 0; a < 4; ++a)
                #pragma unroll
                for (int bb = 0; bb < 4; ++bb)
                    dst[a * 4 + bb] =
                        fmaf(A[a * 4 + 0], B[0 * 4 + bb], fmaf(A[a * 4 + 1], B[1 * 4 + bb],
                        fmaf(A[a * 4 + 2], B[2 * 4 + bb], A[a * 4 + 3] * B[3 * 4 + bb])));
        }
    } else {
        // ---- pack (coalesced + ballot), one wave per sample row ----
        int gid  = (blockIdx.x - KSEG) * 256 + threadIdx.x;
        int row  = gid >> 6;
        int lane = threadIdx.x & 63;
        const float* r = data + (size_t)row * NSITES;
        #pragma unroll
        for (int w = 0; w < 12; ++w) {
            u64 m = __ballot(r[w * 64 + lane] == 1.0f);
            if (lane == 0) packed[(size_t)w * BS_TOT + row] = m;
        }
        float v = (lane < 16) ? r[768 + lane] : 0.0f;
        u64 m = __ballot((lane < 16) && (v == 1.0f));
        if (lane == 0) packed[(size_t)12 * BS_TOT + row] = m;
    }
}

// 49-bit window of data bits starting at n0 (max word index 12, in bounds)
__device__ __forceinline__ u64 bit_window(const u64* __restrict__ packed, int n0, int b) {
    int a0 = n0 >> 6, s = n0 & 63;
    u64 w0 = packed[(size_t)a0 * BS_TOT + b];
    u64 w1 = packed[(size_t)(a0 + 1) * BS_TOT + b];
    return s ? ((w0 >> s) | (w1 << (64 - s))) : w0;
}

// ================= kernel 2: per-segment products from quads (R9-verified) =========
__global__ __launch_bounds__(256) void phase1q_kernel(const float* __restrict__ tensors,
                                                      const u64* __restrict__ packed,
                                                      const float* __restrict__ QQ,
                                                      float* __restrict__ Pbuf) {
    const int b = blockIdx.x * 256 + threadIdx.x;
    const int k = blockIdx.y;
    const int n0 = k * GSEG;

    __shared__ __align__(16) float lt[NQUAD * 16 * 20];
    {
        const float4* src = (const float4*)(QQ + (size_t)k * NQUAD * 16 * 16);
        float4* dst = (float4*)lt;
        for (int e = threadIdx.x; e < NQUAD * 16 * 4; e += 256) {  // 768 float4s
            int q = e >> 6, c = (e >> 2) & 15, j = e & 3;
            dst[q * 80 + c * 5 + j] = src[e];
        }
    }
    __syncthreads();

    u64 win = bit_window(packed, n0, b);
    const float4* ltf4 = (const float4*)lt;

    float4 P0, P1, P2, P3;
    {
        const int c0 = (int)(win & 15ull);
        const float4* mi = ltf4 + (c0 * 5);
        P0 = mi[0]; P1 = mi[1]; P2 = mi[2]; P3 = mi[3];
    }
    #pragma unroll
    for (int q = 1; q < NQUAD; ++q) {
        const int cq = (int)((win >> (4 * q)) & 15ull);
        const float4* mi = ltf4 + (q * 80 + cq * 5);
        float4 m0 = mi[0], m1 = mi[1], m2 = mi[2], m3 = mi[3];
        MM4(P0, P1, P2, P3);
    }
    {   // final single site n0+48: block-uniform tensor -> s_load; per-lane select
        const float* t48 = tensors + (size_t)(n0 + 48) * 32;
        const bool s48 = ((win >> 48) & 1ull) != 0;
        float4 m0 = make_float4(s48 ? t48[0]  : t48[1],  s48 ? t48[2]  : t48[3],
                                s48 ? t48[4]  : t48[5],  s48 ? t48[6]  : t48[7]);
        float4 m1 = make_float4(s48 ? t48[8]  : t48[9],  s48 ? t48[10] : t48[11],
                                s48 ? t48[12] : t48[13], s48 ? t48[14] : t48[15]);
        float4 m2 = make_float4(s48 ? t48[16] : t48[17], s48 ? t48[18] : t48[19],
                                s48 ? t48[20] : t48[21], s48 ? t48[22] : t48[23]);
        float4 m3 = make_float4(s48 ? t48[24] : t48[25], s48 ? t48[26] : t48[27],
                                s48 ? t48[28] : t48[29], s48 ? t48[30] : t48[31]);
        MM4(P0, P1, P2, P3);
    }

    float4* pb = (float4*)(Pbuf + ((size_t)k * BS_TOT + b) * 16);
    pb[0] = P0; pb[1] = P1; pb[2] = P2; pb[3] = P3;
}

// ================= kernel 3: prefix scan over 15 segment products =================
// prefix[k][r][b] = (e0 * P_0 * ... * P_{k-1})[r]; chunked loads for ILP
__global__ __launch_bounds__(256) void scan_kernel(const float* __restrict__ Pbuf,
                                                   float* __restrict__ prefix) {
    int b = blockIdx.x * 256 + threadIdx.x;
    float l0 = 1.0f, l1 = 0.0f, l2 = 0.0f, l3 = 0.0f;
    const float4* base = (const float4*)Pbuf + (size_t)b * 4;
    #pragma unroll
    for (int kc = 0; kc < 3; ++kc) {              // 3 chunks of 5 segments
        float4 R[5][4];
        #pragma unroll
        for (int j = 0; j < 5; ++j) {
            const float4* pb = base + (size_t)(kc * 5 + j) * BS_TOT * 4;
            R[j][0] = pb[0]; R[j][1] = pb[1]; R[j][2] = pb[2]; R[j][3] = pb[3];
        }
        #pragma unroll
        for (int j = 0; j < 5; ++j) {
            const int k = kc * 5 + j;
            prefix[((size_t)k * 4 + 0) * BS_TOT + b] = l0;
            prefix[((size_t)k * 4 + 1) * BS_TOT + b] = l1;
            prefix[((size_t)k * 4 + 2) * BS_TOT + b] = l2;
            prefix[((size_t)k * 4 + 3) * BS_TOT + b] = l3;
            float n0 = fmaf(l0, R[j][0].x, fmaf(l1, R[j][1].x, fmaf(l2, R[j][2].x, l3 * R[j][3].x)));
            float n1 = fmaf(l0, R[j][0].y, fmaf(l1, R[j][1].y, fmaf(l2, R[j][2].y, l3 * R[j][3].y)));
            float n2 = fmaf(l0, R[j][0].z, fmaf(l1, R[j][1].z, fmaf(l2, R[j][2].z, l3 * R[j][3].z)));
            float n3 = fmaf(l0, R[j][0].w, fmaf(l1, R[j][1].w, fmaf(l2, R[j][2].w, l3 * R[j][3].w)));
            l0 = n0; l1 = n1; l2 = n2; l3 = n3;
        }
    }
    prefix[((size_t)15 * 4 + 0) * BS_TOT + b] = l0;
    prefix[((size_t)15 * 4 + 1) * BS_TOT + b] = l1;
    prefix[((size_t)15 * 4 + 2) * BS_TOT + b] = l2;
    prefix[((size_t)15 * 4 + 3) * BS_TOT + b] = l3;
}

// ================= kernel 4: log-softmax walk, 2 samples/thread =================
// blockIdx.y = segment (TRULY uniform -> s_load, R3-proven SGPR=112 codegen).
// Each thread walks samples b0 and b0+8192; shared scalar tensor stream amortized 2x.
__global__ __launch_bounds__(256) void walk2_kernel(const float* __restrict__ tensors,
                                                    const u64* __restrict__ packed,
                                                    const float* __restrict__ prefix,
                                                    float* __restrict__ res) {
    const int k  = blockIdx.y;
    const int n0 = k * GSEG;
    const int b0 = blockIdx.x * 256 + threadIdx.x;
    const int b1 = b0 + BS_TOT / 2;
    const float* tb = tensors + (size_t)n0 * 32;   // block-uniform

    u64 winA = bit_window(packed, n0, b0);
    u64 winB = bit_window(packed, n0, b1);

    float lA0 = prefix[((size_t)k * 4 + 0) * BS_TOT + b0];
    float lA1 = prefix[((size_t)k * 4 + 1) * BS_TOT + b0];
    float lA2 = prefix[((size_t)k * 4 + 2) * BS_TOT + b0];
    float lA3 = prefix[((size_t)k * 4 + 3) * BS_TOT + b0];
    float lB0 = prefix[((size_t)k * 4 + 0) * BS_TOT + b1];
    float lB1 = prefix[((size_t)k * 4 + 1) * BS_TOT + b1];
    float lB2 = prefix[((size_t)k * 4 + 2) * BS_TOT + b1];
    float lB3 = prefix[((size_t)k * 4 + 3) * BS_TOT + b1];
    float anA = 0.0f, alA = 0.0f, anB = 0.0f, alB = 0.0f;

    #pragma unroll 4
    for (int i = 0; i < GSEG; ++i) {
        const float* ts = tb + i * 32;
        STEPV(((winA >> i) & 1ull) != 0, ts, lA0,lA1,lA2,lA3, anA, alA);
        STEPV(((winB >> i) & 1ull) != 0, ts, lB0,lB1,lB2,lB3, anB, alB);
    }
    res[(size_t)k * BS_TOT + b0] = anA - 0.6931471805599453f * alA;
    res[(size_t)k * BS_TOT + b1] = anB - 0.6931471805599453f * alB;
}

// ================= kernel 5: reduce partials =================
__global__ __launch_bounds__(256) void reduce_kernel(const float* __restrict__ res,
                                                     float* __restrict__ out) {
    int b = blockIdx.x * 256 + threadIdx.x;
    float a = 0.0f;
    #pragma unroll
    for (int k = 0; k < KSEG; ++k) a += res[(size_t)k * BS_TOT + b];
    out[b] = a;
}

// ================= round-0 fallback (known-correct) =================
__global__ __launch_bounds__(64) void amps_chain_kernel(
    const float* __restrict__ data, const float* __restrict__ tensors,
    float* __restrict__ out)
{
    int b = blockIdx.x * blockDim.x + threadIdx.x;
    if (b >= BS_TOT) return;
    const float* row = data + (size_t)b * NSITES;
    float left0 = 1.0f, left1 = 0.0f, left2 = 0.0f, left3 = 0.0f;
    float acc_nat = 0.0f, acc_l2 = 0.0f;
    for (int n = 0; n < NSITES; ++n) {
        STEP(row[n] == 1.0f, tensors + (size_t)n * 32);
    }
    out[b] = acc_nat - 0.6931471805599453f * acc_l2;
}

extern "C" void kernel_launch(void* const* d_in, const int* in_sizes, int n_in,
                              void* d_out, int out_size, void* d_ws, size_t ws_size,
                              hipStream_t stream) {
    const float* data    = (const float*)d_in[0];   // (16384, 784) float32
    const float* tensors = (const float*)d_in[1];   // (784, 4, 4, 2) float32
    float* out = (float*)d_out;                     // (16384,) float32

    const size_t packed_bytes = (size_t)13 * BS_TOT * 8;                   //  1,703,936
    const size_t Pbuf_bytes   = (size_t)(KSEG - 1) * BS_TOT * 16 * 4;      // 15,728,640
    const size_t QQ_bytes     = (size_t)KSEG * NQUAD * 16 * 16 * 4;        //    786,432
    const size_t prefix_bytes = (size_t)KSEG * 4 * BS_TOT * 4;             //  4,194,304
    const size_t res_bytes    = (size_t)KSEG * BS_TOT * 4;                 //  1,048,576
    const size_t need = packed_bytes + Pbuf_bytes + QQ_bytes + prefix_bytes + res_bytes;

    if (ws_size < need) {
        hipLaunchKernelGGL(amps_chain_kernel, dim3(BS_TOT / 64), dim3(64), 0, stream,
                           data, tensors, out);
        return;
    }

    char* wsb = (char*)d_ws;
    u64*   packed = (u64*)wsb;
    float* Pbuf   = (float*)(wsb + packed_bytes);
    float* QQ     = (float*)(wsb + packed_bytes + Pbuf_bytes);
    float* prefix = (float*)(wsb + packed_bytes + Pbuf_bytes + QQ_bytes);
    float* res    = (float*)(wsb + packed_bytes + Pbuf_bytes + QQ_bytes + prefix_bytes);

    hipLaunchKernelGGL(fused_pre_kernel, dim3(KSEG + (BS_TOT * 64) / 256), dim3(256), 0, stream,
                       tensors, data, QQ, packed);
    hipLaunchKernelGGL(phase1q_kernel,   dim3(BS_TOT / 256, KSEG - 1), dim3(256), 0, stream,
                       tensors, packed, QQ, Pbuf);
    hipLaunchKernelGGL(scan_kernel,      dim3(BS_TOT / 256), dim3(256), 0, stream,
                       Pbuf, prefix);
    hipLaunchKernelGGL(walk2_kernel,     dim3(BS_TOT / 2 / 256, KSEG), dim3(256), 0, stream,
                       tensors, packed, prefix, res);
    hipLaunchKernelGGL(reduce_kernel,    dim3(BS_TOT / 256), dim3(256), 0, stream, res, out);
}

// Round 12
// 57.749 us; speedup vs baseline: 1.1329x; 1.1329x over previous
//
#include <hip/hip_runtime.h>

#define NSITES 784
#define BS_TOT 16384
#define KSEG 16
#define GSEG 49     // 16*49 = 784; 49 = 12 quads * 4 + 1 site
#define NQUAD 12

typedef unsigned long long u64;

// ---------------- per-site step, fully parameterized (round-0/R8 verified math) ----------
// c0..c7 = 8 float4s of the site tensor in layout order (t_[0..31], [l][r][p] flat):
//   c{2l}   = (T[l][0][0], T[l][0][1], T[l][1][0], T[l][1][1])
//   c{2l+1} = (T[l][2][0], T[l][2][1], T[l][3][0], T[l][3][1])
#define STEP_REGV(bitset, c0,c1,c2,c3,c4,c5,c6,c7, L0,L1,L2,L3, AN,AL) do { \
  float p00 = fmaf(L0, c0.x, fmaf(L1, c2.x, fmaf(L2, c4.x, L3 * c6.x))); \
  float p01 = fmaf(L0, c0.y, fmaf(L1, c2.y, fmaf(L2, c4.y, L3 * c6.y))); \
  float p10 = fmaf(L0, c0.z, fmaf(L1, c2.z, fmaf(L2, c4.z, L3 * c6.z))); \
  float p11 = fmaf(L0, c0.w, fmaf(L1, c2.w, fmaf(L2, c4.w, L3 * c6.w))); \
  float p20 = fmaf(L0, c1.x, fmaf(L1, c3.x, fmaf(L2, c5.x, L3 * c7.x))); \
  float p21 = fmaf(L0, c1.y, fmaf(L1, c3.y, fmaf(L2, c5.y, L3 * c7.y))); \
  float p30 = fmaf(L0, c1.z, fmaf(L1, c3.z, fmaf(L2, c5.z, L3 * c7.z))); \
  float p31 = fmaf(L0, c1.w, fmaf(L1, c3.w, fmaf(L2, c5.w, L3 * c7.w))); \
  bool s_ = (bitset); \
  float mx_ = fmaxf(p00, p01); \
  float ch_ = s_ ? p00 : p01; \
  AN += (ch_ - mx_); \
  float ad_ = fabsf(p00 - p01); \
  AL += __builtin_amdgcn_logf(1.0f + __builtin_amdgcn_exp2f(-ad_ * 1.4426950408889634f)); \
  L0 = s_ ? p00 : p01; \
  L1 = s_ ? p10 : p11; \
  L2 = s_ ? p20 : p21; \
  L3 = s_ ? p30 : p31; \
} while (0)

// scalar-pointer STEP (round-0 verified) -- fallback kernel only
#define STEP(sbit, TP) do {                                                          \
    const float* t_ = (TP);                                                          \
    float p00 = fmaf(left0, t_[0],  fmaf(left1, t_[8],  fmaf(left2, t_[16], left3 * t_[24]))); \
    float p01 = fmaf(left0, t_[1],  fmaf(left1, t_[9],  fmaf(left2, t_[17], left3 * t_[25]))); \
    float p10 = fmaf(left0, t_[2],  fmaf(left1, t_[10], fmaf(left2, t_[18], left3 * t_[26]))); \
    float p11 = fmaf(left0, t_[3],  fmaf(left1, t_[11], fmaf(left2, t_[19], left3 * t_[27]))); \
    float p20 = fmaf(left0, t_[4],  fmaf(left1, t_[12], fmaf(left2, t_[20], left3 * t_[28]))); \
    float p21 = fmaf(left0, t_[5],  fmaf(left1, t_[13], fmaf(left2, t_[21], left3 * t_[29]))); \
    float p30 = fmaf(left0, t_[6],  fmaf(left1, t_[14], fmaf(left2, t_[22], left3 * t_[30]))); \
    float p31 = fmaf(left0, t_[7],  fmaf(left1, t_[15], fmaf(left2, t_[23], left3 * t_[31]))); \
    bool s_ = (sbit);                                                                \
    float mx_ = fmaxf(p00, p01);                                                     \
    float ch_ = s_ ? p00 : p01;                                                      \
    acc_nat += (ch_ - mx_);                                                          \
    float ad_ = fabsf(p00 - p01);                                                    \
    acc_l2 += __builtin_amdgcn_logf(1.0f + __builtin_amdgcn_exp2f(-ad_ * 1.4426950408889634f)); \
    left0 = s_ ? p00 : p01;                                                          \
    left1 = s_ ? p10 : p11;                                                          \
    left2 = s_ ? p20 : p21;                                                          \
    left3 = s_ ? p30 : p31;                                                          \
} while (0)

// Q_row = P_row * M  (rows of M in float4 m0..m3)
#define MM_ROW(Q, Pr) do {                                                           \
    Q.x = fmaf(Pr.x, m0.x, fmaf(Pr.y, m1.x, fmaf(Pr.z, m2.x, Pr.w * m3.x)));         \
    Q.y = fmaf(Pr.x, m0.y, fmaf(Pr.y, m1.y, fmaf(Pr.z, m2.y, Pr.w * m3.y)));         \
    Q.z = fmaf(Pr.x, m0.z, fmaf(Pr.y, m1.z, fmaf(Pr.z, m2.z, Pr.w * m3.z)));         \
    Q.w = fmaf(Pr.x, m0.w, fmaf(Pr.y, m1.w, fmaf(Pr.z, m2.w, Pr.w * m3.w)));         \
} while (0)

#define MM4(P0,P1,P2,P3) do { float4 Q0,Q1,Q2,Q3; \
    MM_ROW(Q0,P0); MM_ROW(Q1,P1); MM_ROW(Q2,P2); MM_ROW(Q3,P3); \
    P0=Q0; P1=Q1; P2=Q2; P3=Q3; } while (0)

// ================= kernel 1: fused [pp_qq (16 blocks)] + [pack (4096 blocks)] =========
__global__ __launch_bounds__(256) void fused_pre_kernel(const float* __restrict__ tensors,
                                                        const float* __restrict__ data,
                                                        float* __restrict__ QQ,
                                                        u64* __restrict__ packed) {
    if (blockIdx.x < KSEG) {
        __shared__ float sPP[24][4][16];
        const int k = blockIdx.x;
        const int t = threadIdx.x;
        const int n0 = k * GSEG;

        if (t < 96) {                      // 24 pairs x 4 combos
            const int j = t >> 2, c2 = t & 3;
            const float* t0 = tensors + (size_t)(n0 + 2 * j) * 32;
            const float* t1 = tensors + (size_t)(n0 + 2 * j + 1) * 32;
            const int p0 = (c2 & 1) ? 0 : 1;
            const int p1 = (c2 & 2) ? 0 : 1;
            float A[4][4], B[4][4];
            #pragma unroll
            for (int l = 0; l < 4; ++l)
                #pragma unroll
                for (int r = 0; r < 4; ++r) {
                    A[l][r] = t0[l * 8 + r * 2 + p0];
                    B[l][r] = t1[l * 8 + r * 2 + p1];
                }
            #pragma unroll
            for (int a = 0; a < 4; ++a)
                #pragma unroll
                for (int bb = 0; bb < 4; ++bb)
                    sPP[j][c2][a * 4 + bb] =
                        fmaf(A[a][0], B[0][bb], fmaf(A[a][1], B[1][bb],
                        fmaf(A[a][2], B[2][bb], A[a][3] * B[3][bb])));
        }
        __syncthreads();

        if (t < 192) {                     // 12 quads x 16 combos
            const int q = t >> 4, c = t & 15;
            const float* A = sPP[2 * q][c & 3];
            const float* B = sPP[2 * q + 1][(c >> 2) & 3];
            float* dst = QQ + ((size_t)(k * NQUAD + q) * 16 + c) * 16;
            #pragma unroll
            for (int a = 0; a < 4; ++a)
                #pragma unroll
                for (int bb = 0; bb < 4; ++bb)
                    dst[a * 4 + bb] =
                        fmaf(A[a * 4 + 0], B[0 * 4 + bb], fmaf(A[a * 4 + 1], B[1 * 4 + bb],
                        fmaf(A[a * 4 + 2], B[2 * 4 + bb], A[a * 4 + 3] * B[3 * 4 + bb])));
        }
    } else {
        int gid  = (blockIdx.x - KSEG) * 256 + threadIdx.x;
        int row  = gid >> 6;
        int lane = threadIdx.x & 63;
        const float* r = data + (size_t)row * NSITES;
        #pragma unroll
        for (int w = 0; w < 12; ++w) {
            u64 m = __ballot(r[w * 64 + lane] == 1.0f);
            if (lane == 0) packed[(size_t)w * BS_TOT + row] = m;
        }
        float v = (lane < 16) ? r[768 + lane] : 0.0f;
        u64 m = __ballot((lane < 16) && (v == 1.0f));
        if (lane == 0) packed[(size_t)12 * BS_TOT + row] = m;
    }
}

// 49-bit window of data bits starting at n0 (max word index 12, in bounds)
__device__ __forceinline__ u64 bit_window(const u64* __restrict__ packed, int n0, int b) {
    int a0 = n0 >> 6, s = n0 & 63;
    u64 w0 = packed[(size_t)a0 * BS_TOT + b];
    u64 w1 = packed[(size_t)(a0 + 1) * BS_TOT + b];
    return s ? ((w0 >> s) | (w1 << (64 - s))) : w0;
}

// ================= kernel 2: per-segment products from quads (R9-verified) =========
__global__ __launch_bounds__(256) void phase1q_kernel(const float* __restrict__ tensors,
                                                      const u64* __restrict__ packed,
                                                      const float* __restrict__ QQ,
                                                      float* __restrict__ Pbuf) {
    const int b = blockIdx.x * 256 + threadIdx.x;
    const int k = blockIdx.y;
    const int n0 = k * GSEG;

    __shared__ __align__(16) float lt[NQUAD * 16 * 20];
    {
        const float4* src = (const float4*)(QQ + (size_t)k * NQUAD * 16 * 16);
        float4* dst = (float4*)lt;
        for (int e = threadIdx.x; e < NQUAD * 16 * 4; e += 256) {  // 768 float4s
            int q = e >> 6, c = (e >> 2) & 15, j = e & 3;
            dst[q * 80 + c * 5 + j] = src[e];
        }
    }
    __syncthreads();

    u64 win = bit_window(packed, n0, b);
    const float4* ltf4 = (const float4*)lt;

    float4 P0, P1, P2, P3;
    {
        const int c0 = (int)(win & 15ull);
        const float4* mi = ltf4 + (c0 * 5);
        P0 = mi[0]; P1 = mi[1]; P2 = mi[2]; P3 = mi[3];
    }
    #pragma unroll
    for (int q = 1; q < NQUAD; ++q) {
        const int cq = (int)((win >> (4 * q)) & 15ull);
        const float4* mi = ltf4 + (q * 80 + cq * 5);
        float4 m0 = mi[0], m1 = mi[1], m2 = mi[2], m3 = mi[3];
        MM4(P0, P1, P2, P3);
    }
    {   // final single site n0+48: block-uniform tensor -> s_load; per-lane select
        const float* t48 = tensors + (size_t)(n0 + 48) * 32;
        const bool s48 = ((win >> 48) & 1ull) != 0;
        float4 m0 = make_float4(s48 ? t48[0]  : t48[1],  s48 ? t48[2]  : t48[3],
                                s48 ? t48[4]  : t48[5],  s48 ? t48[6]  : t48[7]);
        float4 m1 = make_float4(s48 ? t48[8]  : t48[9],  s48 ? t48[10] : t48[11],
                                s48 ? t48[12] : t48[13], s48 ? t48[14] : t48[15]);
        float4 m2 = make_float4(s48 ? t48[16] : t48[17], s48 ? t48[18] : t48[19],
                                s48 ? t48[20] : t48[21], s48 ? t48[22] : t48[23]);
        float4 m3 = make_float4(s48 ? t48[24] : t48[25], s48 ? t48[26] : t48[27],
                                s48 ? t48[28] : t48[29], s48 ? t48[30] : t48[31]);
        MM4(P0, P1, P2, P3);
    }

    float4* pb = (float4*)(Pbuf + ((size_t)k * BS_TOT + b) * 16);
    pb[0] = P0; pb[1] = P1; pb[2] = P2; pb[3] = P3;
}

// ================= kernel 3: prefix scan over 15 segment products (R10) =========
__global__ __launch_bounds__(256) void scan_kernel(const float* __restrict__ Pbuf,
                                                   float* __restrict__ prefix) {
    int b = blockIdx.x * 256 + threadIdx.x;
    float l0 = 1.0f, l1 = 0.0f, l2 = 0.0f, l3 = 0.0f;
    const float4* base = (const float4*)Pbuf + (size_t)b * 4;
    #pragma unroll
    for (int kc = 0; kc < 3; ++kc) {
        float4 R[5][4];
        #pragma unroll
        for (int j = 0; j < 5; ++j) {
            const float4* pb = base + (size_t)(kc * 5 + j) * BS_TOT * 4;
            R[j][0] = pb[0]; R[j][1] = pb[1]; R[j][2] = pb[2]; R[j][3] = pb[3];
        }
        #pragma unroll
        for (int j = 0; j < 5; ++j) {
            const int k = kc * 5 + j;
            prefix[((size_t)k * 4 + 0) * BS_TOT + b] = l0;
            prefix[((size_t)k * 4 + 1) * BS_TOT + b] = l1;
            prefix[((size_t)k * 4 + 2) * BS_TOT + b] = l2;
            prefix[((size_t)k * 4 + 3) * BS_TOT + b] = l3;
            float n0 = fmaf(l0, R[j][0].x, fmaf(l1, R[j][1].x, fmaf(l2, R[j][2].x, l3 * R[j][3].x)));
            float n1 = fmaf(l0, R[j][0].y, fmaf(l1, R[j][1].y, fmaf(l2, R[j][2].y, l3 * R[j][3].y)));
            float n2 = fmaf(l0, R[j][0].z, fmaf(l1, R[j][1].z, fmaf(l2, R[j][2].z, l3 * R[j][3].z)));
            float n3 = fmaf(l0, R[j][0].w, fmaf(l1, R[j][1].w, fmaf(l2, R[j][2].w, l3 * R[j][3].w)));
            l0 = n0; l1 = n1; l2 = n2; l3 = n3;
        }
    }
    prefix[((size_t)15 * 4 + 0) * BS_TOT + b] = l0;
    prefix[((size_t)15 * 4 + 1) * BS_TOT + b] = l1;
    prefix[((size_t)15 * 4 + 2) * BS_TOT + b] = l2;
    prefix[((size_t)15 * 4 + 3) * BS_TOT + b] = l3;
}

// ================= kernel 4: log-softmax walk, 4 samples/thread from LDS =========
// grid (16 chunks, 16 segments) = 256 blocks (~1/CU). Segment tensors staged to LDS once;
// each broadcast ds_read_b128 feeds 4 samples -> LDS pipe cost /4 vs R8.
__global__ __launch_bounds__(256) void walk4_kernel(const float* __restrict__ tensors,
                                                    const u64* __restrict__ packed,
                                                    const float* __restrict__ prefix,
                                                    float* __restrict__ res) {
    const int k  = blockIdx.y;
    const int n0 = k * GSEG;

    __shared__ __align__(16) float lt[GSEG * 32];   // 6272 B
    {
        const float4* src = (const float4*)(tensors + (size_t)n0 * 32);
        float4* dst = (float4*)lt;
        for (int e = threadIdx.x; e < GSEG * 8; e += 256) dst[e] = src[e];
    }
    __syncthreads();

    const int t  = threadIdx.x;
    const int bA = blockIdx.x * 1024 + t;        // 4 samples, stride 256
    const int bB = bA + 256;
    const int bC = bA + 512;
    const int bD = bA + 768;

    u64 winA = bit_window(packed, n0, bA);
    u64 winB = bit_window(packed, n0, bB);
    u64 winC = bit_window(packed, n0, bC);
    u64 winD = bit_window(packed, n0, bD);

    const size_t pk = (size_t)k * 4 * BS_TOT;
    float lA0 = prefix[pk + 0 * BS_TOT + bA], lA1 = prefix[pk + 1 * BS_TOT + bA];
    float lA2 = prefix[pk + 2 * BS_TOT + bA], lA3 = prefix[pk + 3 * BS_TOT + bA];
    float lB0 = prefix[pk + 0 * BS_TOT + bB], lB1 = prefix[pk + 1 * BS_TOT + bB];
    float lB2 = prefix[pk + 2 * BS_TOT + bB], lB3 = prefix[pk + 3 * BS_TOT + bB];
    float lC0 = prefix[pk + 0 * BS_TOT + bC], lC1 = prefix[pk + 1 * BS_TOT + bC];
    float lC2 = prefix[pk + 2 * BS_TOT + bC], lC3 = prefix[pk + 3 * BS_TOT + bC];
    float lD0 = prefix[pk + 0 * BS_TOT + bD], lD1 = prefix[pk + 1 * BS_TOT + bD];
    float lD2 = prefix[pk + 2 * BS_TOT + bD], lD3 = prefix[pk + 3 * BS_TOT + bD];
    float anA = 0.0f, alA = 0.0f, anB = 0.0f, alB = 0.0f;
    float anC = 0.0f, alC = 0.0f, anD = 0.0f, alD = 0.0f;

    const float4* ltf4 = (const float4*)lt;
    #pragma unroll 7
    for (int i = 0; i < GSEG; ++i) {
        float4 c0 = ltf4[i * 8 + 0], c1 = ltf4[i * 8 + 1];
        float4 c2 = ltf4[i * 8 + 2], c3 = ltf4[i * 8 + 3];
        float4 c4 = ltf4[i * 8 + 4], c5 = ltf4[i * 8 + 5];
        float4 c6 = ltf4[i * 8 + 6], c7 = ltf4[i * 8 + 7];
        STEP_REGV(((winA >> i) & 1ull) != 0, c0,c1,c2,c3,c4,c5,c6,c7, lA0,lA1,lA2,lA3, anA,alA);
        STEP_REGV(((winB >> i) & 1ull) != 0, c0,c1,c2,c3,c4,c5,c6,c7, lB0,lB1,lB2,lB3, anB,alB);
        STEP_REGV(((winC >> i) & 1ull) != 0, c0,c1,c2,c3,c4,c5,c6,c7, lC0,lC1,lC2,lC3, anC,alC);
        STEP_REGV(((winD >> i) & 1ull) != 0, c0,c1,c2,c3,c4,c5,c6,c7, lD0,lD1,lD2,lD3, anD,alD);
    }

    const float LN2 = 0.6931471805599453f;
    res[(size_t)k * BS_TOT + bA] = anA - LN2 * alA;
    res[(size_t)k * BS_TOT + bB] = anB - LN2 * alB;
    res[(size_t)k * BS_TOT + bC] = anC - LN2 * alC;
    res[(size_t)k * BS_TOT + bD] = anD - LN2 * alD;
}

// ================= kernel 5: reduce partials =================
__global__ __launch_bounds__(256) void reduce_kernel(const float* __restrict__ res,
                                                     float* __restrict__ out) {
    int b = blockIdx.x * 256 + threadIdx.x;
    float a = 0.0f;
    #pragma unroll
    for (int k = 0; k < KSEG; ++k) a += res[(size_t)k * BS_TOT + b];
    out[b] = a;
}

// ================= round-0 fallback (known-correct) =================
__global__ __launch_bounds__(64) void amps_chain_kernel(
    const float* __restrict__ data, const float* __restrict__ tensors,
    float* __restrict__ out)
{
    int b = blockIdx.x * blockDim.x + threadIdx.x;
    if (b >= BS_TOT) return;
    const float* row = data + (size_t)b * NSITES;
    float left0 = 1.0f, left1 = 0.0f, left2 = 0.0f, left3 = 0.0f;
    float acc_nat = 0.0f, acc_l2 = 0.0f;
    for (int n = 0; n < NSITES; ++n) {
        STEP(row[n] == 1.0f, tensors + (size_t)n * 32);
    }
    out[b] = acc_nat - 0.6931471805599453f * acc_l2;
}

extern "C" void kernel_launch(void* const* d_in, const int* in_sizes, int n_in,
                              void* d_out, int out_size, void* d_ws, size_t ws_size,
                              hipStream_t stream) {
    const float* data    = (const float*)d_in[0];   // (16384, 784) float32
    const float* tensors = (const float*)d_in[1];   // (784, 4, 4, 2) float32
    float* out = (float*)d_out;                     // (16384,) float32

    const size_t packed_bytes = (size_t)13 * BS_TOT * 8;                   //  1,703,936
    const size_t Pbuf_bytes   = (size_t)(KSEG - 1) * BS_TOT * 16 * 4;      // 15,728,640
    const size_t QQ_bytes     = (size_t)KSEG * NQUAD * 16 * 16 * 4;        //    786,432
    const size_t prefix_bytes = (size_t)KSEG * 4 * BS_TOT * 4;             //  4,194,304
    const size_t res_bytes    = (size_t)KSEG * BS_TOT * 4;                 //  1,048,576
    const size_t need = packed_bytes + Pbuf_bytes + QQ_bytes + prefix_bytes + res_bytes;

    if (ws_size < need) {
        hipLaunchKernelGGL(amps_chain_kernel, dim3(BS_TOT / 64), dim3(64), 0, stream,
                           data, tensors, out);
        return;
    }

    char* wsb = (char*)d_ws;
    u64*   packed = (u64*)wsb;
    float* Pbuf   = (float*)(wsb + packed_bytes);
    float* QQ     = (float*)(wsb + packed_bytes + Pbuf_bytes);
    float* prefix = (float*)(wsb + packed_bytes + Pbuf_bytes + QQ_bytes);
    float* res    = (float*)(wsb + packed_bytes + Pbuf_bytes + QQ_bytes + prefix_bytes);

    hipLaunchKernelGGL(fused_pre_kernel, dim3(KSEG + (BS_TOT * 64) / 256), dim3(256), 0, stream,
                       tensors, data, QQ, packed);
    hipLaunchKernelGGL(phase1q_kernel,   dim3(BS_TOT / 256, KSEG - 1), dim3(256), 0, stream,
                       tensors, packed, QQ, Pbuf);
    hipLaunchKernelGGL(scan_kernel,      dim3(BS_TOT / 256), dim3(256), 0, stream,
                       Pbuf, prefix);
    hipLaunchKernelGGL(walk4_kernel,     dim3(BS_TOT / 1024, KSEG), dim3(256), 0, stream,
                       tensors, packed, prefix, res);
    hipLaunchKernelGGL(reduce_kernel,    dim3(BS_TOT / 256), dim3(256), 0, stream, res, out);
}